// Round 1
// baseline (1043.760 us; speedup 1.0000x reference)
//
#include <hip/hip_runtime.h>

#define TOKENS 2048
#define HD 1024
#define NEXP 16
#define TWO_I 4096
#define ID 2048

typedef short short8 __attribute__((ext_vector_type(8)));
typedef float f32x4 __attribute__((ext_vector_type(4)));

static __device__ __forceinline__ unsigned short f2bf(float f) {
    union { float f; unsigned u; } v; v.f = f;
    unsigned r = v.u + 0x7FFFu + ((v.u >> 16) & 1u);
    return (unsigned short)(r >> 16);
}

// ---------------- hidden fp32 -> bf16 ----------------
__global__ __launch_bounds__(256) void cvt_kernel(const float* __restrict__ hs,
                                                  unsigned short* __restrict__ hb) {
    int i = (blockIdx.x * 256 + threadIdx.x) * 4;
    float4 v = *(const float4*)(hs + i);
    union { unsigned short b[4]; float2 f2; } u;
    u.b[0] = f2bf(v.x); u.b[1] = f2bf(v.y); u.b[2] = f2bf(v.z); u.b[3] = f2bf(v.w);
    *(float2*)(hb + i) = u.f2;
}

// ---------------- router: logits -> softmax -> top4 -> renorm ----------------
__global__ __launch_bounds__(256) void router_kernel(
    const float* __restrict__ hs, const float* __restrict__ rw,
    const float* __restrict__ rb, float* __restrict__ topk_w_out,
    int* __restrict__ topk_idx, int* __restrict__ counts) {
    const int wave = threadIdx.x >> 6;
    const int lane = threadIdx.x & 63;
    const int t = blockIdx.x * 4 + wave;

    float h[16];
#pragma unroll
    for (int j = 0; j < 16; ++j) h[j] = hs[t * HD + j * 64 + lane];

    __shared__ float lg[4][NEXP];
#pragma unroll
    for (int e = 0; e < NEXP; ++e) {
        float acc = 0.f;
#pragma unroll
        for (int j = 0; j < 16; ++j) acc += h[j] * rw[e * HD + j * 64 + lane];
#pragma unroll
        for (int s = 32; s > 0; s >>= 1) acc += __shfl_xor(acc, s);
        if (lane == 0) lg[wave][e] = acc + rb[e];
    }
    if (lane == 0) {
        float mx = lg[wave][0];
        for (int e = 1; e < NEXP; ++e) mx = fmaxf(mx, lg[wave][e]);
        float pr[NEXP];
        for (int e = 0; e < NEXP; ++e) pr[e] = __expf(lg[wave][e] - mx);
        int idx[4]; float wv[4]; float sum4 = 0.f;
        for (int k = 0; k < 4; ++k) {
            int bi = 0; float bv = -1.f;
            for (int e = 0; e < NEXP; ++e)
                if (pr[e] > bv) { bv = pr[e]; bi = e; }
            idx[k] = bi; wv[k] = bv; pr[bi] = -2.f; sum4 += bv;
        }
        for (int k = 0; k < 4; ++k) {
            topk_w_out[t * 4 + k] = wv[k] / sum4;
            topk_idx[t * 4 + k] = idx[k];
            atomicAdd(&counts[idx[k]], 1);
        }
    }
}

// ---------------- prefix scan over 16 counts ----------------
__global__ void scan_kernel(const int* __restrict__ counts, int* __restrict__ offsets,
                            int* __restrict__ cursor) {
    if (threadIdx.x == 0 && blockIdx.x == 0) {
        int o = 0;
        for (int e = 0; e < NEXP; ++e) { offsets[e] = o; cursor[e] = o; o += counts[e]; }
        offsets[NEXP] = o;
    }
}

// ---------------- build per-expert token lists ----------------
__global__ __launch_bounds__(256) void build_kernel(
    const int* __restrict__ topk_idx, const float* __restrict__ topk_w,
    int* __restrict__ cursor, int* __restrict__ token_list, float* __restrict__ slot_w) {
    int t = blockIdx.x * 256 + threadIdx.x;
    for (int k = 0; k < 4; ++k) {
        int e = topk_idx[t * 4 + k];
        int pos = atomicAdd(&cursor[e], 1);
        token_list[pos] = t;
        slot_w[pos] = topk_w[t * 4 + k];
    }
}

// ---------------- grouped GEMM1 + bias + clamp + GLU -> activated bf16 ----------------
__global__ __launch_bounds__(256) void gemm1_kernel(
    const unsigned short* __restrict__ hb, const float* __restrict__ gup,
    const float* __restrict__ gub, const int* __restrict__ offsets,
    const int* __restrict__ token_list, unsigned short* __restrict__ act) {
    const int e = blockIdx.z;
    const int so = offsets[e];
    const int ne = offsets[e + 1] - so;
    const int row0 = blockIdx.y * 64;
    if (row0 >= ne) return;
    const int n0 = blockIdx.x * 64;

    __shared__ unsigned short Al[64][40];
    __shared__ unsigned short Bt[64][40];

    const int tid = threadIdx.x;
    const int lane = tid & 63;
    const int wave = tid >> 6;
    const int m = lane & 15;
    const int q = lane >> 4;

    const int ar = tid >> 2;
    const int ac = (tid & 3) * 8;
    int arow = row0 + ar; if (arow >= ne) arow = ne - 1;
    const int tok = token_list[so + arow];
    const unsigned short* aptr = hb + tok * HD + ac;

    const int bk = tid >> 3;
    const int bn = (tid & 7) * 8;
    const float* bptr = gup + (size_t)e * HD * TWO_I + (size_t)bk * TWO_I + n0 + bn;

    f32x4 acc[4] = {{0,0,0,0},{0,0,0,0},{0,0,0,0},{0,0,0,0}};

    for (int k0 = 0; k0 < HD; k0 += 32) {
        float4 av = *(const float4*)(aptr + k0);
        *(float4*)(&Al[ar][ac]) = av;
        const float* bp = bptr + (size_t)k0 * TWO_I;
        float4 b0 = *(const float4*)(bp);
        float4 b1 = *(const float4*)(bp + 4);
        Bt[bn + 0][bk] = f2bf(b0.x); Bt[bn + 1][bk] = f2bf(b0.y);
        Bt[bn + 2][bk] = f2bf(b0.z); Bt[bn + 3][bk] = f2bf(b0.w);
        Bt[bn + 4][bk] = f2bf(b1.x); Bt[bn + 5][bk] = f2bf(b1.y);
        Bt[bn + 6][bk] = f2bf(b1.z); Bt[bn + 7][bk] = f2bf(b1.w);
        __syncthreads();
        short8 af = *(const short8*)(&Al[wave * 16 + m][q * 8]);
#pragma unroll
        for (int c = 0; c < 4; ++c) {
            short8 bf = *(const short8*)(&Bt[c * 16 + m][q * 8]);
            acc[c] = __builtin_amdgcn_mfma_f32_16x16x32_bf16(af, bf, acc[c], 0, 0, 0);
        }
        __syncthreads();
    }

#pragma unroll
    for (int c = 0; c < 4; ++c) {
        const int n = n0 + c * 16 + m;
        const float bias = gub[e * TWO_I + n];
#pragma unroll
        for (int r = 0; r < 4; ++r) {
            const int grow = row0 + wave * 16 + q * 4 + r;
            float v = acc[c][r] + bias;
            float pv = __shfl_xor(v, 1);
            float gate = (m & 1) ? pv : v;
            float up   = (m & 1) ? v : pv;
            gate = fminf(gate, 7.0f);
            up = fminf(fmaxf(up, -7.0f), 7.0f);
            float glu = gate / (1.0f + __expf(-1.702f * gate));
            float a = (up + 1.0f) * glu;
            if (!(m & 1) && grow < ne)
                act[(size_t)(so + grow) * ID + (n >> 1)] = f2bf(a);
        }
    }
}

// ---------------- grouped GEMM2 + bias + weight + atomic combine ----------------
__global__ __launch_bounds__(256) void gemm2_kernel(
    const unsigned short* __restrict__ act, const float* __restrict__ dwp,
    const float* __restrict__ dwb, const int* __restrict__ offsets,
    const int* __restrict__ token_list, const float* __restrict__ slot_w,
    float* __restrict__ out) {
    const int e = blockIdx.z;
    const int so = offsets[e];
    const int ne = offsets[e + 1] - so;
    const int row0 = blockIdx.y * 64;
    if (row0 >= ne) return;
    const int n0 = blockIdx.x * 64;

    __shared__ unsigned short Al[64][40];
    __shared__ unsigned short Bt[64][40];

    const int tid = threadIdx.x;
    const int lane = tid & 63;
    const int wave = tid >> 6;
    const int m = lane & 15;
    const int q = lane >> 4;

    const int ar = tid >> 2;
    const int ac = (tid & 3) * 8;
    int arow = row0 + ar; if (arow >= ne) arow = ne - 1;
    const unsigned short* aptr = act + (size_t)(so + arow) * ID + ac;

    const int bk = tid >> 3;
    const int bn = (tid & 7) * 8;
    const float* bptr = dwp + (size_t)e * ID * HD + (size_t)bk * HD + n0 + bn;

    f32x4 acc[4] = {{0,0,0,0},{0,0,0,0},{0,0,0,0},{0,0,0,0}};

    for (int k0 = 0; k0 < ID; k0 += 32) {
        float4 av = *(const float4*)(aptr + k0);
        *(float4*)(&Al[ar][ac]) = av;
        const float* bp = bptr + (size_t)k0 * HD;
        float4 b0 = *(const float4*)(bp);
        float4 b1 = *(const float4*)(bp + 4);
        Bt[bn + 0][bk] = f2bf(b0.x); Bt[bn + 1][bk] = f2bf(b0.y);
        Bt[bn + 2][bk] = f2bf(b0.z); Bt[bn + 3][bk] = f2bf(b0.w);
        Bt[bn + 4][bk] = f2bf(b1.x); Bt[bn + 5][bk] = f2bf(b1.y);
        Bt[bn + 6][bk] = f2bf(b1.z); Bt[bn + 7][bk] = f2bf(b1.w);
        __syncthreads();
        short8 af = *(const short8*)(&Al[wave * 16 + m][q * 8]);
#pragma unroll
        for (int c = 0; c < 4; ++c) {
            short8 bf = *(const short8*)(&Bt[c * 16 + m][q * 8]);
            acc[c] = __builtin_amdgcn_mfma_f32_16x16x32_bf16(af, bf, acc[c], 0, 0, 0);
        }
        __syncthreads();
    }

#pragma unroll
    for (int r = 0; r < 4; ++r) {
        const int grow = row0 + wave * 16 + q * 4 + r;
        if (grow < ne) {
            const int slot = so + grow;
            const int tok = token_list[slot];
            const float wgt = slot_w[slot];
#pragma unroll
            for (int c = 0; c < 4; ++c) {
                const int n = n0 + c * 16 + m;
                float val = (acc[c][r] + dwb[e * HD + n]) * wgt;
                atomicAdd(&out[tok * HD + n], val);
            }
        }
    }
}

extern "C" void kernel_launch(void* const* d_in, const int* in_sizes, int n_in,
                              void* d_out, int out_size, void* d_ws, size_t ws_size,
                              hipStream_t stream) {
    const float* hs  = (const float*)d_in[0];
    const float* rw  = (const float*)d_in[1];
    const float* rb  = (const float*)d_in[2];
    const float* gup = (const float*)d_in[3];
    const float* gub = (const float*)d_in[4];
    const float* dwp = (const float*)d_in[5];
    const float* dwb = (const float*)d_in[6];

    float* out = (float*)d_out;                       // [2048,1024] fp32
    float* topk_w = out + (size_t)TOKENS * HD;        // [2048,4] fp32

    char* w = (char*)d_ws;
    int* counts     = (int*)(w + 0);                  // 16 ints
    int* cursor     = (int*)(w + 64);                 // 16 ints
    int* offsets    = (int*)(w + 128);                // 17 ints
    int* token_list = (int*)(w + 256);                // 8192 ints
    float* slot_w   = (float*)(w + 256 + 32768);      // 8192 floats
    int* topk_idx   = (int*)(w + 256 + 65536);        // 8192 ints
    unsigned short* hb  = (unsigned short*)(w + (1 << 20));   // [2048,1024] bf16
    unsigned short* act = (unsigned short*)(w + (size_t)(5 << 20)); // [8192,2048] bf16

    hipMemsetAsync(w, 0, 256, stream);
    hipMemsetAsync(out, 0, (size_t)TOKENS * HD * sizeof(float), stream);

    cvt_kernel<<<2048, 256, 0, stream>>>(hs, hb);
    router_kernel<<<512, 256, 0, stream>>>(hs, rw, rb, topk_w, topk_idx, counts);
    scan_kernel<<<1, 64, 0, stream>>>(counts, offsets, cursor);
    build_kernel<<<8, 256, 0, stream>>>(topk_idx, topk_w, cursor, token_list, slot_w);
    gemm1_kernel<<<dim3(TWO_I / 64, TOKENS / 64, NEXP), 256, 0, stream>>>(
        hb, gup, gub, offsets, token_list, act);
    gemm2_kernel<<<dim3(HD / 64, TOKENS / 64, NEXP), 256, 0, stream>>>(
        act, dwp, dwb, offsets, token_list, slot_w, out);
}

// Round 2
// 818.482 us; speedup vs baseline: 1.2752x; 1.2752x over previous
//
#include <hip/hip_runtime.h>

#define TOKENS 2048
#define HD 1024
#define NEXP 16
#define TWO_I 4096
#define ID 2048

typedef short short8 __attribute__((ext_vector_type(8)));
typedef float f32x4 __attribute__((ext_vector_type(4)));
typedef unsigned short ushort;

static __device__ __forceinline__ ushort f2bf(float f) {
    union { float f; unsigned u; } v; v.f = f;
    unsigned r = v.u + 0x7FFFu + ((v.u >> 16) & 1u);
    return (ushort)(r >> 16);
}

static __device__ __forceinline__ void gload_lds16(const void* g, void* l) {
    __builtin_amdgcn_global_load_lds(
        (const __attribute__((address_space(1))) unsigned int*)(g),
        (__attribute__((address_space(3))) unsigned int*)(l), 16, 0, 0);
}

// ---------------- hidden fp32 -> bf16 ----------------
__global__ __launch_bounds__(256) void cvt_kernel(const float* __restrict__ hs,
                                                  ushort* __restrict__ hb) {
    int i = (blockIdx.x * 256 + threadIdx.x) * 4;
    float4 v = *(const float4*)(hs + i);
    union { ushort b[4]; float2 f2; } u;
    u.b[0] = f2bf(v.x); u.b[1] = f2bf(v.y); u.b[2] = f2bf(v.z); u.b[3] = f2bf(v.w);
    *(float2*)(hb + i) = u.f2;
}

// ---------------- weight transpose+convert: [E][K][N] f32 -> [E][N][K] bf16 ----
__global__ __launch_bounds__(256) void transpose_cvt_kernel(
    const float* __restrict__ src, ushort* __restrict__ dst, int K, int N) {
    const int e = blockIdx.z;
    const int n0 = blockIdx.x * 64;
    const int k0 = blockIdx.y * 64;
    __shared__ float T[64][68];
    const float* s = src + (size_t)e * K * N + (size_t)k0 * N + n0;
    const int r = threadIdx.x >> 4;
    const int c4 = (threadIdx.x & 15) * 4;
#pragma unroll
    for (int i = 0; i < 64; i += 16) {
        float4 v = *(const float4*)(s + (size_t)(r + i) * N + c4);
        T[r + i][c4 + 0] = v.x; T[r + i][c4 + 1] = v.y;
        T[r + i][c4 + 2] = v.z; T[r + i][c4 + 3] = v.w;
    }
    __syncthreads();
    const int n = threadIdx.x >> 2;
    const int kc = (threadIdx.x & 3) * 16;
    union { ushort b[16]; short8 v[2]; } o;
#pragma unroll
    for (int j = 0; j < 16; ++j) o.b[j] = f2bf(T[kc + j][n]);
    ushort* d = dst + (size_t)e * N * K + (size_t)(n0 + n) * K + k0 + kc;
    *(short8*)(d) = o.v[0];
    *(short8*)(d + 8) = o.v[1];
}

// ---------------- router: logits -> softmax -> top4 -> renorm ----------------
__global__ __launch_bounds__(256) void router_kernel(
    const float* __restrict__ hs, const float* __restrict__ rw,
    const float* __restrict__ rb, float* __restrict__ topk_w_out,
    int* __restrict__ topk_idx, int* __restrict__ counts) {
    const int wave = threadIdx.x >> 6;
    const int lane = threadIdx.x & 63;
    const int t = blockIdx.x * 4 + wave;

    float h[16];
#pragma unroll
    for (int j = 0; j < 16; ++j) h[j] = hs[t * HD + j * 64 + lane];

    __shared__ float lg[4][NEXP];
#pragma unroll
    for (int e = 0; e < NEXP; ++e) {
        float acc = 0.f;
#pragma unroll
        for (int j = 0; j < 16; ++j) acc += h[j] * rw[e * HD + j * 64 + lane];
#pragma unroll
        for (int s = 32; s > 0; s >>= 1) acc += __shfl_xor(acc, s);
        if (lane == 0) lg[wave][e] = acc + rb[e];
    }
    if (lane == 0) {
        float mx = lg[wave][0];
        for (int e = 1; e < NEXP; ++e) mx = fmaxf(mx, lg[wave][e]);
        float pr[NEXP];
        for (int e = 0; e < NEXP; ++e) pr[e] = __expf(lg[wave][e] - mx);
        int idx[4]; float wv[4]; float sum4 = 0.f;
        for (int k = 0; k < 4; ++k) {
            int bi = 0; float bv = -1.f;
            for (int e = 0; e < NEXP; ++e)
                if (pr[e] > bv) { bv = pr[e]; bi = e; }
            idx[k] = bi; wv[k] = bv; pr[bi] = -2.f; sum4 += bv;
        }
        for (int k = 0; k < 4; ++k) {
            topk_w_out[t * 4 + k] = wv[k] / sum4;
            topk_idx[t * 4 + k] = idx[k];
            atomicAdd(&counts[idx[k]], 1);
        }
    }
}

// ---------------- prefix scan over 16 counts ----------------
__global__ void scan_kernel(const int* __restrict__ counts, int* __restrict__ offsets,
                            int* __restrict__ cursor) {
    if (threadIdx.x == 0 && blockIdx.x == 0) {
        int o = 0;
        for (int e = 0; e < NEXP; ++e) { offsets[e] = o; cursor[e] = o; o += counts[e]; }
        offsets[NEXP] = o;
    }
}

// ---------------- build per-expert token lists ----------------
__global__ __launch_bounds__(256) void build_kernel(
    const int* __restrict__ topk_idx, const float* __restrict__ topk_w,
    int* __restrict__ cursor, int* __restrict__ token_list, float* __restrict__ slot_w) {
    int t = blockIdx.x * 256 + threadIdx.x;
    for (int k = 0; k < 4; ++k) {
        int e = topk_idx[t * 4 + k];
        int pos = atomicAdd(&cursor[e], 1);
        token_list[pos] = t;
        slot_w[pos] = topk_w[t * 4 + k];
    }
}

// ============ NEW PATH: m97-style 128x128 grouped GEMMs on bf16 weights ============

// ---- GEMM1: act[slot][I] = GLU((hb[tok] . gupT[e]) + bias) ----
__global__ __launch_bounds__(256) void gemm1_t_kernel(
    const ushort* __restrict__ hb, const ushort* __restrict__ gupT,
    const float* __restrict__ gub, const int* __restrict__ offsets,
    const int* __restrict__ token_list, ushort* __restrict__ act) {
    const int e = blockIdx.z;
    const int so = offsets[e];
    const int ne = offsets[e + 1] - so;
    const int row0 = blockIdx.y * 128;
    if (row0 >= ne) return;
    const int n0 = blockIdx.x * 128;

    __shared__ ushort As[128 * 32];
    __shared__ ushort Bs[128 * 32];

    const int tid = threadIdx.x;
    const int lane = tid & 63;
    const int w = tid >> 6;
    const int m = lane & 15;
    const int q = lane >> 4;
    const int wm = (w >> 1) * 64;
    const int wn = (w & 1) * 64;

    // staging: issue j in {0,1}: row = j*64 + tid/4, col element = (tid&3)*8
    const int r0 = tid >> 2;
    const int ce = (tid & 3) * 8;
    int ar0 = row0 + r0;       if (ar0 >= ne) ar0 = ne - 1;
    int ar1 = row0 + 64 + r0;  if (ar1 >= ne) ar1 = ne - 1;
    const ushort* ga0 = hb + (size_t)token_list[so + ar0] * HD + ce;
    const ushort* ga1 = hb + (size_t)token_list[so + ar1] * HD + ce;
    const ushort* gb0 = gupT + (size_t)e * TWO_I * HD + (size_t)(n0 + r0) * HD + ce;
    const ushort* gb1 = gb0 + (size_t)64 * HD;
    ushort* lA0 = As + w * 512;
    ushort* lA1 = As + 2048 + w * 512;
    ushort* lB0 = Bs + w * 512;
    ushort* lB1 = Bs + 2048 + w * 512;

    f32x4 acc[4][4] = {};

    for (int k0 = 0; k0 < HD; k0 += 32) {
        gload_lds16(ga0 + k0, lA0);
        gload_lds16(ga1 + k0, lA1);
        gload_lds16(gb0 + k0, lB0);
        gload_lds16(gb1 + k0, lB1);
        asm volatile("s_waitcnt vmcnt(0)" ::: "memory");
        __syncthreads();
        short8 af[4], bf[4];
#pragma unroll
        for (int rt = 0; rt < 4; ++rt)
            af[rt] = *(const short8*)(As + (wm + rt * 16 + m) * 32 + q * 8);
#pragma unroll
        for (int c = 0; c < 4; ++c)
            bf[c] = *(const short8*)(Bs + (wn + c * 16 + m) * 32 + q * 8);
#pragma unroll
        for (int rt = 0; rt < 4; ++rt)
#pragma unroll
            for (int c = 0; c < 4; ++c)
                acc[rt][c] = __builtin_amdgcn_mfma_f32_16x16x32_bf16(af[rt], bf[c], acc[rt][c], 0, 0, 0);
        __syncthreads();
    }

#pragma unroll
    for (int c = 0; c < 4; ++c) {
        const int n = n0 + wn + c * 16 + m;
        const float bias = gub[e * TWO_I + n];
#pragma unroll
        for (int rt = 0; rt < 4; ++rt) {
#pragma unroll
            for (int rr = 0; rr < 4; ++rr) {
                const int grow = row0 + wm + rt * 16 + q * 4 + rr;
                float v = acc[rt][c][rr] + bias;
                float pv = __shfl_xor(v, 1);
                float gate = (m & 1) ? pv : v;
                float up   = (m & 1) ? v : pv;
                gate = fminf(gate, 7.0f);
                up = fminf(fmaxf(up, -7.0f), 7.0f);
                float glu = gate / (1.0f + __expf(-1.702f * gate));
                float a = (up + 1.0f) * glu;
                if (!(m & 1) && grow < ne)
                    act[(size_t)(so + grow) * ID + (n >> 1)] = f2bf(a);
            }
        }
    }
}

// ---- GEMM2: out[tok] += w * (act[slot] . downT[e] + bias) ----
__global__ __launch_bounds__(256) void gemm2_t_kernel(
    const ushort* __restrict__ act, const ushort* __restrict__ downT,
    const float* __restrict__ dwb, const int* __restrict__ offsets,
    const int* __restrict__ token_list, const float* __restrict__ slot_w,
    float* __restrict__ out) {
    const int e = blockIdx.z;
    const int so = offsets[e];
    const int ne = offsets[e + 1] - so;
    const int row0 = blockIdx.y * 128;
    if (row0 >= ne) return;
    const int n0 = blockIdx.x * 128;

    __shared__ ushort As[128 * 32];
    __shared__ ushort Bs[128 * 32];

    const int tid = threadIdx.x;
    const int lane = tid & 63;
    const int w = tid >> 6;
    const int m = lane & 15;
    const int q = lane >> 4;
    const int wm = (w >> 1) * 64;
    const int wn = (w & 1) * 64;

    const int r0 = tid >> 2;
    const int ce = (tid & 3) * 8;
    // A rows (slots) are contiguous per expert: no gather. act has 128 rows of slack.
    const ushort* ga0 = act + (size_t)(so + row0 + r0) * ID + ce;
    const ushort* ga1 = ga0 + (size_t)64 * ID;
    const ushort* gb0 = downT + (size_t)e * HD * ID + (size_t)(n0 + r0) * ID + ce;
    const ushort* gb1 = gb0 + (size_t)64 * ID;
    ushort* lA0 = As + w * 512;
    ushort* lA1 = As + 2048 + w * 512;
    ushort* lB0 = Bs + w * 512;
    ushort* lB1 = Bs + 2048 + w * 512;

    f32x4 acc[4][4] = {};

    for (int k0 = 0; k0 < ID; k0 += 32) {
        gload_lds16(ga0 + k0, lA0);
        gload_lds16(ga1 + k0, lA1);
        gload_lds16(gb0 + k0, lB0);
        gload_lds16(gb1 + k0, lB1);
        asm volatile("s_waitcnt vmcnt(0)" ::: "memory");
        __syncthreads();
        short8 af[4], bf[4];
#pragma unroll
        for (int rt = 0; rt < 4; ++rt)
            af[rt] = *(const short8*)(As + (wm + rt * 16 + m) * 32 + q * 8);
#pragma unroll
        for (int c = 0; c < 4; ++c)
            bf[c] = *(const short8*)(Bs + (wn + c * 16 + m) * 32 + q * 8);
#pragma unroll
        for (int rt = 0; rt < 4; ++rt)
#pragma unroll
            for (int c = 0; c < 4; ++c)
                acc[rt][c] = __builtin_amdgcn_mfma_f32_16x16x32_bf16(af[rt], bf[c], acc[rt][c], 0, 0, 0);
        __syncthreads();
    }

    float bias[4];
#pragma unroll
    for (int c = 0; c < 4; ++c) bias[c] = dwb[e * HD + n0 + wn + c * 16 + m];

#pragma unroll
    for (int rt = 0; rt < 4; ++rt) {
#pragma unroll
        for (int rr = 0; rr < 4; ++rr) {
            const int grow = row0 + wm + rt * 16 + q * 4 + rr;
            if (grow < ne) {
                const int slot = so + grow;
                const int tok = token_list[slot];
                const float wgt = slot_w[slot];
#pragma unroll
                for (int c = 0; c < 4; ++c) {
                    const int n = n0 + wn + c * 16 + m;
                    atomicAdd(&out[tok * HD + n], (acc[rt][c][rr] + bias[c]) * wgt);
                }
            }
        }
    }
}

// ============ FALLBACK PATH (round-1 kernels, used only if ws too small) ============

__global__ __launch_bounds__(256) void gemm1_fb_kernel(
    const ushort* __restrict__ hb, const float* __restrict__ gup,
    const float* __restrict__ gub, const int* __restrict__ offsets,
    const int* __restrict__ token_list, ushort* __restrict__ act) {
    const int e = blockIdx.z;
    const int so = offsets[e];
    const int ne = offsets[e + 1] - so;
    const int row0 = blockIdx.y * 64;
    if (row0 >= ne) return;
    const int n0 = blockIdx.x * 64;
    __shared__ ushort Al[64][40];
    __shared__ ushort Bt[64][40];
    const int tid = threadIdx.x;
    const int lane = tid & 63;
    const int wave = tid >> 6;
    const int m = lane & 15;
    const int q = lane >> 4;
    const int ar = tid >> 2;
    const int ac = (tid & 3) * 8;
    int arow = row0 + ar; if (arow >= ne) arow = ne - 1;
    const int tok = token_list[so + arow];
    const ushort* aptr = hb + tok * HD + ac;
    const int bk = tid >> 3;
    const int bn = (tid & 7) * 8;
    const float* bptr = gup + (size_t)e * HD * TWO_I + (size_t)bk * TWO_I + n0 + bn;
    f32x4 acc[4] = {{0,0,0,0},{0,0,0,0},{0,0,0,0},{0,0,0,0}};
    for (int k0 = 0; k0 < HD; k0 += 32) {
        float4 av = *(const float4*)(aptr + k0);
        *(float4*)(&Al[ar][ac]) = av;
        const float* bp = bptr + (size_t)k0 * TWO_I;
        float4 b0 = *(const float4*)(bp);
        float4 b1 = *(const float4*)(bp + 4);
        Bt[bn + 0][bk] = f2bf(b0.x); Bt[bn + 1][bk] = f2bf(b0.y);
        Bt[bn + 2][bk] = f2bf(b0.z); Bt[bn + 3][bk] = f2bf(b0.w);
        Bt[bn + 4][bk] = f2bf(b1.x); Bt[bn + 5][bk] = f2bf(b1.y);
        Bt[bn + 6][bk] = f2bf(b1.z); Bt[bn + 7][bk] = f2bf(b1.w);
        __syncthreads();
        short8 af = *(const short8*)(&Al[wave * 16 + m][q * 8]);
#pragma unroll
        for (int c = 0; c < 4; ++c) {
            short8 bf = *(const short8*)(&Bt[c * 16 + m][q * 8]);
            acc[c] = __builtin_amdgcn_mfma_f32_16x16x32_bf16(af, bf, acc[c], 0, 0, 0);
        }
        __syncthreads();
    }
#pragma unroll
    for (int c = 0; c < 4; ++c) {
        const int n = n0 + c * 16 + m;
        const float bias = gub[e * TWO_I + n];
#pragma unroll
        for (int r = 0; r < 4; ++r) {
            const int grow = row0 + wave * 16 + q * 4 + r;
            float v = acc[c][r] + bias;
            float pv = __shfl_xor(v, 1);
            float gate = (m & 1) ? pv : v;
            float up   = (m & 1) ? v : pv;
            gate = fminf(gate, 7.0f);
            up = fminf(fmaxf(up, -7.0f), 7.0f);
            float glu = gate / (1.0f + __expf(-1.702f * gate));
            float a = (up + 1.0f) * glu;
            if (!(m & 1) && grow < ne)
                act[(size_t)(so + grow) * ID + (n >> 1)] = f2bf(a);
        }
    }
}

__global__ __launch_bounds__(256) void gemm2_fb_kernel(
    const ushort* __restrict__ act, const float* __restrict__ dwp,
    const float* __restrict__ dwb, const int* __restrict__ offsets,
    const int* __restrict__ token_list, const float* __restrict__ slot_w,
    float* __restrict__ out) {
    const int e = blockIdx.z;
    const int so = offsets[e];
    const int ne = offsets[e + 1] - so;
    const int row0 = blockIdx.y * 64;
    if (row0 >= ne) return;
    const int n0 = blockIdx.x * 64;
    __shared__ ushort Al[64][40];
    __shared__ ushort Bt[64][40];
    const int tid = threadIdx.x;
    const int lane = tid & 63;
    const int wave = tid >> 6;
    const int m = lane & 15;
    const int q = lane >> 4;
    const int ar = tid >> 2;
    const int ac = (tid & 3) * 8;
    int arow = row0 + ar; if (arow >= ne) arow = ne - 1;
    const ushort* aptr = act + (size_t)(so + arow) * ID + ac;
    const int bk = tid >> 3;
    const int bn = (tid & 7) * 8;
    const float* bptr = dwp + (size_t)e * ID * HD + (size_t)bk * HD + n0 + bn;
    f32x4 acc[4] = {{0,0,0,0},{0,0,0,0},{0,0,0,0},{0,0,0,0}};
    for (int k0 = 0; k0 < ID; k0 += 32) {
        float4 av = *(const float4*)(aptr + k0);
        *(float4*)(&Al[ar][ac]) = av;
        const float* bp = bptr + (size_t)k0 * HD;
        float4 b0 = *(const float4*)(bp);
        float4 b1 = *(const float4*)(bp + 4);
        Bt[bn + 0][bk] = f2bf(b0.x); Bt[bn + 1][bk] = f2bf(b0.y);
        Bt[bn + 2][bk] = f2bf(b0.z); Bt[bn + 3][bk] = f2bf(b0.w);
        Bt[bn + 4][bk] = f2bf(b1.x); Bt[bn + 5][bk] = f2bf(b1.y);
        Bt[bn + 6][bk] = f2bf(b1.z); Bt[bn + 7][bk] = f2bf(b1.w);
        __syncthreads();
        short8 af = *(const short8*)(&Al[wave * 16 + m][q * 8]);
#pragma unroll
        for (int c = 0; c < 4; ++c) {
            short8 bf = *(const short8*)(&Bt[c * 16 + m][q * 8]);
            acc[c] = __builtin_amdgcn_mfma_f32_16x16x32_bf16(af, bf, acc[c], 0, 0, 0);
        }
        __syncthreads();
    }
#pragma unroll
    for (int r = 0; r < 4; ++r) {
        const int grow = row0 + wave * 16 + q * 4 + r;
        if (grow < ne) {
            const int slot = so + grow;
            const int tok = token_list[slot];
            const float wgt = slot_w[slot];
#pragma unroll
            for (int c = 0; c < 4; ++c) {
                const int n = n0 + c * 16 + m;
                atomicAdd(&out[tok * HD + n], (acc[c][r] + dwb[e * HD + n]) * wgt);
            }
        }
    }
}

extern "C" void kernel_launch(void* const* d_in, const int* in_sizes, int n_in,
                              void* d_out, int out_size, void* d_ws, size_t ws_size,
                              hipStream_t stream) {
    const float* hs  = (const float*)d_in[0];
    const float* rw  = (const float*)d_in[1];
    const float* rb  = (const float*)d_in[2];
    const float* gup = (const float*)d_in[3];
    const float* gub = (const float*)d_in[4];
    const float* dwp = (const float*)d_in[5];
    const float* dwb = (const float*)d_in[6];

    float* out = (float*)d_out;                       // [2048,1024] fp32
    float* topk_w = out + (size_t)TOKENS * HD;        // [2048,4] fp32

    char* w = (char*)d_ws;
    int* counts     = (int*)(w + 0);
    int* cursor     = (int*)(w + 64);
    int* offsets    = (int*)(w + 128);
    int* token_list = (int*)(w + 256);
    float* slot_w   = (float*)(w + 256 + 32768);
    int* topk_idx   = (int*)(w + 256 + 65536);
    ushort* hb      = (ushort*)(w + (1 << 20));                 // 4 MB
    ushort* act     = (ushort*)(w + (size_t)(6 << 20));         // 8320x2048 bf16 (~32.5MB)
    ushort* gupT    = (ushort*)(w + (size_t)(41 << 20));        // 128 MB
    ushort* downT   = (ushort*)(w + (size_t)(169 << 20));       // 64 MB
    const size_t need = (size_t)(233) << 20;

    hipMemsetAsync(w, 0, 256, stream);
    hipMemsetAsync(out, 0, (size_t)TOKENS * HD * sizeof(float), stream);

    cvt_kernel<<<2048, 256, 0, stream>>>(hs, hb);
    router_kernel<<<512, 256, 0, stream>>>(hs, rw, rb, topk_w, topk_idx, counts);
    scan_kernel<<<1, 64, 0, stream>>>(counts, offsets, cursor);
    build_kernel<<<8, 256, 0, stream>>>(topk_idx, topk_w, cursor, token_list, slot_w);

    if (ws_size >= need) {
        transpose_cvt_kernel<<<dim3(TWO_I / 64, HD / 64, NEXP), 256, 0, stream>>>(
            gup, gupT, HD, TWO_I);
        transpose_cvt_kernel<<<dim3(HD / 64, ID / 64, NEXP), 256, 0, stream>>>(
            dwp, downT, ID, HD);
        gemm1_t_kernel<<<dim3(TWO_I / 128, TOKENS / 128, NEXP), 256, 0, stream>>>(
            hb, gupT, gub, offsets, token_list, act);
        gemm2_t_kernel<<<dim3(HD / 128, TOKENS / 128, NEXP), 256, 0, stream>>>(
            act, downT, dwb, offsets, token_list, slot_w, out);
    } else {
        // fallback: fp32 weights converted in-tile (round-1 path); act at 6MB offset
        gemm1_fb_kernel<<<dim3(TWO_I / 64, TOKENS / 64, NEXP), 256, 0, stream>>>(
            hb, gup, gub, offsets, token_list, act);
        gemm2_fb_kernel<<<dim3(HD / 64, TOKENS / 64, NEXP), 256, 0, stream>>>(
            act, dwp, dwb, offsets, token_list, slot_w, out);
    }
}